// Round 1
// baseline (223.047 us; speedup 1.0000x reference)
//
#include <hip/hip_runtime.h>

// B=2, S=2048, E=1024, H=16, D=64.  M = B*S = 4096.
// Pipeline: prep (f32->bf16 + weight transposes) -> GEMM1 (QKV, writes q/k [bh][s][d],
// v transposed [bh][d][s]) -> flash attention (writes o [m][1024] bf16) -> GEMM3 (f32 out).

typedef __attribute__((ext_vector_type(8))) __bf16 bf16x8;
typedef __attribute__((ext_vector_type(4))) __bf16 bf16x4;
typedef __attribute__((ext_vector_type(4))) float  f32x4;

#define LOG2E 1.4426950408889634f
#define SM_SC (0.125f * LOG2E)   // softmax scale folded with log2(e)

static __device__ __forceinline__ void gl2lds16(const void* g, void* l) {
    __builtin_amdgcn_global_load_lds(
        (__attribute__((address_space(1))) void*)(void*)g,
        (__attribute__((address_space(3))) void*)l, 16, 0, 0);
}

// ---------------- prep kernels ----------------
__global__ void prep_x_kern(const float* __restrict__ x, __bf16* __restrict__ xb) {
    int i = (blockIdx.x * 256 + threadIdx.x) * 4;
    f32x4 v = *(const f32x4*)(x + i);
    bf16x4 o = { (__bf16)v[0], (__bf16)v[1], (__bf16)v[2], (__bf16)v[3] };
    *(bf16x4*)(xb + i) = o;
}

// wt[n][k] = W_p[h][k][d],  n = p*1024 + h*64 + d (p in {q,k,v}); bias[n] = b_p[h*64+d]
__global__ void prep_wqkv_kern(const float* __restrict__ Wq, const float* __restrict__ Wk,
                               const float* __restrict__ Wv, const float* __restrict__ bq,
                               const float* __restrict__ bk, const float* __restrict__ bv,
                               __bf16* __restrict__ wt, float* __restrict__ bias) {
    int idx = blockIdx.x * 256 + threadIdx.x;     // 0..3145727
    int n = idx >> 10, kk = idx & 1023;
    int p = n >> 10, rm = n & 1023;
    int h = rm >> 6, d = rm & 63;
    const float* W = (p == 0) ? Wq : (p == 1) ? Wk : Wv;
    wt[idx] = (__bf16)W[(h << 16) + (kk << 6) + d];
    if (idx < 3072) {
        int p2 = idx >> 10, rm2 = idx & 1023;
        const float* bb = (p2 == 0) ? bq : (p2 == 1) ? bk : bv;
        bias[idx] = bb[rm2];
    }
}

// wt[n][k] = W_o[k][n]
__global__ void prep_wo_kern(const float* __restrict__ Wo, __bf16* __restrict__ wt) {
    int idx = blockIdx.x * 256 + threadIdx.x;    // 0..1048575
    int n = idx >> 10, kk = idx & 1023;
    wt[idx] = (__bf16)Wo[(kk << 10) + n];
}

// ---------------- GEMM: C[M][N] = A[M][1024] * Bt[N][1024]^T (+bias) ----------------
// 128x128 tile, BK=64, 4 waves each computing 64x64 via 4x4 of 16x16x32 MFMA.
// EPI=0: scatter bf16 into q/k ([bh][s][d]) and vT ([bh][d][s]) per n = p*1024+h*64+d
// EPI=1: f32 out + bias
template <int EPI>
__global__ void __launch_bounds__(256, 2)
gemm_bt(const __bf16* __restrict__ A, const __bf16* __restrict__ Bt,
        const float* __restrict__ bias,
        __bf16* __restrict__ outq, __bf16* __restrict__ outk, __bf16* __restrict__ outv,
        float* __restrict__ outf)
{
    __shared__ __align__(16) __bf16 As[128 * 64];
    __shared__ __align__(16) __bf16 Bs[128 * 64];
    const int tid = threadIdx.x;
    const int wid = tid >> 6, lane = tid & 63;
    const int r = lane & 15, g = lane >> 4;
    const int m0 = blockIdx.y << 7, n0 = blockIdx.x << 7;
    const int wr = wid >> 1, wc = wid & 1;
    f32x4 acc[4][4] = {};
    for (int k0 = 0; k0 < 1024; k0 += 64) {
        #pragma unroll
        for (int c = 0; c < 4; ++c) {
            int cq = (c * 4 + wid) * 64 + lane;   // 16B chunk index in [0,1024)
            int row = cq >> 3, ci = cq & 7;
            gl2lds16(A  + (((size_t)(m0 + row)) << 10) + k0 + ci * 8, As + (c * 4 + wid) * 512);
            gl2lds16(Bt + (((size_t)(n0 + row)) << 10) + k0 + ci * 8, Bs + (c * 4 + wid) * 512);
        }
        __syncthreads();
        bf16x8 af[2][4], bfr[2][4];
        #pragma unroll
        for (int kh = 0; kh < 2; ++kh)
            #pragma unroll
            for (int i = 0; i < 4; ++i) {
                af[kh][i]  = *(const bf16x8*)&As[(wr * 64 + i * 16 + r) * 64 + kh * 32 + g * 8];
                bfr[kh][i] = *(const bf16x8*)&Bs[(wc * 64 + i * 16 + r) * 64 + kh * 32 + g * 8];
            }
        #pragma unroll
        for (int kh = 0; kh < 2; ++kh)
            #pragma unroll
            for (int mi = 0; mi < 4; ++mi)
                #pragma unroll
                for (int ni = 0; ni < 4; ++ni)
                    acc[mi][ni] = __builtin_amdgcn_mfma_f32_16x16x32_bf16(
                        af[kh][mi], bfr[kh][ni], acc[mi][ni], 0, 0, 0);
        __syncthreads();
    }
    if (EPI == 0) {
        #pragma unroll
        for (int ni = 0; ni < 4; ++ni) {
            int n = n0 + wc * 64 + ni * 16 + r;
            float bv = bias[n];
            int p = n >> 10, rem = n & 1023, h = rem >> 6, d = rem & 63;
            #pragma unroll
            for (int mi = 0; mi < 4; ++mi) {
                int mb = m0 + wr * 64 + mi * 16 + g * 4;
                int b = mb >> 11, s = mb & 2047;
                f32x4 v = acc[mi][ni];
                if (p < 2) {
                    __bf16* dst = (p == 0) ? outq : outk;
                    size_t base = (((size_t)(b * 16 + h)) * 2048 + s) * 64 + d;
                    #pragma unroll
                    for (int j = 0; j < 4; ++j)
                        dst[base + (size_t)j * 64] = (__bf16)(v[j] + bv);
                } else {
                    bf16x4 pk = { (__bf16)(v[0] + bv), (__bf16)(v[1] + bv),
                                  (__bf16)(v[2] + bv), (__bf16)(v[3] + bv) };
                    *(bf16x4*)&outv[(((size_t)(b * 16 + h)) * 64 + d) * 2048 + s] = pk;
                }
            }
        }
    } else {
        #pragma unroll
        for (int ni = 0; ni < 4; ++ni) {
            int n = n0 + wc * 64 + ni * 16 + r;
            float bv = bias[n];
            #pragma unroll
            for (int mi = 0; mi < 4; ++mi) {
                int mb = m0 + wr * 64 + mi * 16 + g * 4;
                f32x4 v = acc[mi][ni];
                #pragma unroll
                for (int j = 0; j < 4; ++j)
                    outf[((size_t)(mb + j) << 10) + n] = v[j] + bv;
            }
        }
    }
}

// ---------------- flash attention ----------------
// grid (16, 32): x = q-block of 128 rows, y = b*16+h. 4 waves, each owns 32 q-rows.
// K tile [64 n][64 d], V^T tile [64 d][64 n] staged in padded LDS; P via per-wave LDS.
__global__ void __launch_bounds__(256, 2)
attn_kern(const __bf16* __restrict__ q, const __bf16* __restrict__ k,
          const __bf16* __restrict__ vT, __bf16* __restrict__ o)
{
    __shared__ __align__(16) __bf16 Ks[64][72];
    __shared__ __align__(16) __bf16 Vs[64][72];
    __shared__ __align__(16) __bf16 Ps[4][32][72];
    const int tid = threadIdx.x, wid = tid >> 6, lane = tid & 63;
    const int r = lane & 15, g = lane >> 4;
    const int bh = blockIdx.y;
    const int b = bh >> 4, h = bh & 15;
    const int qb0 = blockIdx.x << 7;
    const __bf16* qh  = q  + ((size_t)bh << 17);  // 2048*64
    const __bf16* khp = k  + ((size_t)bh << 17);
    const __bf16* vhp = vT + ((size_t)bh << 17);  // [64][2048]

    bf16x8 qf[2][2];  // [kc][mi]
    #pragma unroll
    for (int mi = 0; mi < 2; ++mi)
        #pragma unroll
        for (int kc = 0; kc < 2; ++kc)
            qf[kc][mi] = *(const bf16x8*)&qh[(size_t)(qb0 + wid * 32 + mi * 16 + r) * 64 + kc * 32 + g * 8];

    f32x4 oacc[2][4] = {};
    float mrun[2][4], lrun[2][4];
    #pragma unroll
    for (int mi = 0; mi < 2; ++mi)
        #pragma unroll
        for (int j = 0; j < 4; ++j) { mrun[mi][j] = -3.0e38f; lrun[mi][j] = 0.f; }

    const int wave_last = qb0 + wid * 32 + 31;
    const int ntiles = (qb0 >> 6) + 2;
    for (int t = 0; t < ntiles; ++t) {
        const int n0 = t << 6;
        #pragma unroll
        for (int it = 0; it < 2; ++it) {
            int cq = it * 256 + tid, row = cq >> 3, ci = cq & 7;
            *(bf16x8*)&Ks[row][ci * 8] = *(const bf16x8*)&khp[(size_t)(n0 + row) * 64 + ci * 8];
            *(bf16x8*)&Vs[row][ci * 8] = *(const bf16x8*)&vhp[(size_t)row * 2048 + n0 + ci * 8];
        }
        __syncthreads();
        const bool active = (n0 <= wave_last);
        if (active) {
            f32x4 sacc[2][4] = {};
            #pragma unroll
            for (int kc = 0; kc < 2; ++kc) {
                bf16x8 kf[4];
                #pragma unroll
                for (int ni = 0; ni < 4; ++ni) kf[ni] = *(const bf16x8*)&Ks[ni * 16 + r][kc * 32 + g * 8];
                #pragma unroll
                for (int mi = 0; mi < 2; ++mi)
                    #pragma unroll
                    for (int ni = 0; ni < 4; ++ni)
                        sacc[mi][ni] = __builtin_amdgcn_mfma_f32_16x16x32_bf16(
                            qf[kc][mi], kf[ni], sacc[mi][ni], 0, 0, 0);
            }
            if (n0 + 63 > qb0 + wid * 32) {  // wave-uniform: tile touches the diagonal
                #pragma unroll
                for (int mi = 0; mi < 2; ++mi) {
                    int rowa = qb0 + wid * 32 + mi * 16 + g * 4;
                    #pragma unroll
                    for (int ni = 0; ni < 4; ++ni) {
                        int cola = n0 + ni * 16 + r;
                        #pragma unroll
                        for (int j = 0; j < 4; ++j)
                            if (cola > rowa + j) sacc[mi][ni][j] = -3.0e38f;
                    }
                }
            }
            float fac[2][4];
            #pragma unroll
            for (int mi = 0; mi < 2; ++mi) {
                #pragma unroll
                for (int j = 0; j < 4; ++j) {
                    float rm = fmaxf(fmaxf(sacc[mi][0][j], sacc[mi][1][j]),
                                     fmaxf(sacc[mi][2][j], sacc[mi][3][j]));
                    rm = fmaxf(rm, __shfl_xor(rm, 1));
                    rm = fmaxf(rm, __shfl_xor(rm, 2));
                    rm = fmaxf(rm, __shfl_xor(rm, 4));
                    rm = fmaxf(rm, __shfl_xor(rm, 8));
                    float mnew = fmaxf(mrun[mi][j], rm);
                    float f = exp2f((mrun[mi][j] - mnew) * SM_SC);
                    float ps = 0.f;
                    #pragma unroll
                    for (int ni = 0; ni < 4; ++ni) {
                        float pv = exp2f((sacc[mi][ni][j] - mnew) * SM_SC);
                        sacc[mi][ni][j] = pv;
                        ps += pv;
                    }
                    ps += __shfl_xor(ps, 1); ps += __shfl_xor(ps, 2);
                    ps += __shfl_xor(ps, 4); ps += __shfl_xor(ps, 8);
                    lrun[mi][j] = lrun[mi][j] * f + ps;
                    mrun[mi][j] = mnew;
                    fac[mi][j] = f;
                }
            }
            #pragma unroll
            for (int mi = 0; mi < 2; ++mi)
                #pragma unroll
                for (int ni = 0; ni < 4; ++ni)
                    #pragma unroll
                    for (int j = 0; j < 4; ++j)
                        Ps[wid][mi * 16 + g * 4 + j][ni * 16 + r] = (__bf16)sacc[mi][ni][j];
            #pragma unroll
            for (int mi = 0; mi < 2; ++mi)
                #pragma unroll
                for (int di = 0; di < 4; ++di)
                    #pragma unroll
                    for (int j = 0; j < 4; ++j)
                        oacc[mi][di][j] *= fac[mi][j];
        }
        __syncthreads();
        if (active) {
            #pragma unroll
            for (int kc = 0; kc < 2; ++kc) {
                bf16x8 pf[2], vf[4];
                #pragma unroll
                for (int mi = 0; mi < 2; ++mi) pf[mi] = *(const bf16x8*)&Ps[wid][mi * 16 + r][kc * 32 + g * 8];
                #pragma unroll
                for (int di = 0; di < 4; ++di) vf[di] = *(const bf16x8*)&Vs[di * 16 + r][kc * 32 + g * 8];
                #pragma unroll
                for (int mi = 0; mi < 2; ++mi)
                    #pragma unroll
                    for (int di = 0; di < 4; ++di)
                        oacc[mi][di] = __builtin_amdgcn_mfma_f32_16x16x32_bf16(
                            pf[mi], vf[di], oacc[mi][di], 0, 0, 0);
            }
        }
        __syncthreads();
    }
    #pragma unroll
    for (int mi = 0; mi < 2; ++mi) {
        #pragma unroll
        for (int j = 0; j < 4; ++j) {
            float inv = 1.0f / lrun[mi][j];
            int srow = qb0 + wid * 32 + mi * 16 + g * 4 + j;
            #pragma unroll
            for (int di = 0; di < 4; ++di)
                o[((size_t)(b * 2048 + srow) << 10) + h * 64 + di * 16 + r] =
                    (__bf16)(oacc[mi][di][j] * inv);
        }
    }
}

// ---------------- launch ----------------
extern "C" void kernel_launch(void* const* d_in, const int* in_sizes, int n_in,
                              void* d_out, int out_size, void* d_ws, size_t ws_size,
                              hipStream_t stream) {
    const float* x  = (const float*)d_in[0];
    const float* Wq = (const float*)d_in[1];
    const float* bq = (const float*)d_in[2];
    const float* Wk = (const float*)d_in[3];
    const float* bk = (const float*)d_in[4];
    const float* Wv = (const float*)d_in[5];
    const float* bv = (const float*)d_in[6];
    const float* Wo = (const float*)d_in[7];
    const float* bo = (const float*)d_in[8];
    float* out = (float*)d_out;
    char* ws = (char*)d_ws;
    // workspace layout (bytes), total ~48 MB
    __bf16* xb    = (__bf16*)(ws + 0);          //  8 MB  x as bf16 [4096][1024]
    __bf16* wtqkv = (__bf16*)(ws + 8388608);    //  6 MB  fused qkv weights^T [3072][1024]
    __bf16* wot   = (__bf16*)(ws + 14680064);   //  2 MB  W_o^T [1024][1024]
    float*  biasq = (float*) (ws + 16777216);   // 12 KB  fused qkv bias
    __bf16* qb    = (__bf16*)(ws + 16793600);   //  8 MB  q [32][2048][64]
    __bf16* kb    = (__bf16*)(ws + 25182208);   //  8 MB  k [32][2048][64]
    __bf16* vtb   = (__bf16*)(ws + 33570816);   //  8 MB  v^T [32][64][2048]
    __bf16* ob    = (__bf16*)(ws + 41959424);   //  8 MB  attn out [4096][1024]

    prep_x_kern<<<4096, 256, 0, stream>>>(x, xb);
    prep_wqkv_kern<<<12288, 256, 0, stream>>>(Wq, Wk, Wv, bq, bk, bv, wtqkv, biasq);
    prep_wo_kern<<<4096, 256, 0, stream>>>(Wo, wot);
    gemm_bt<0><<<dim3(24, 32), 256, 0, stream>>>(xb, wtqkv, biasq, qb, kb, vtb, nullptr);
    attn_kern<<<dim3(16, 32), 256, 0, stream>>>(qb, kb, vtb, ob);
    gemm_bt<1><<<dim3(8, 32), 256, 0, stream>>>(ob, wot, bo, nullptr, nullptr, nullptr, out);
}

// Round 2
// 206.857 us; speedup vs baseline: 1.0783x; 1.0783x over previous
//
#include <hip/hip_runtime.h>

// B=2, S=2048, E=1024, H=16, D=64.  M = B*S = 4096.
// Pipeline: prep (f32->bf16 + weight transposes) -> GEMM1 (QKV, writes q/k [bh][s][d],
// v transposed [bh][d][s]) -> flash attention (writes o [m][1024] bf16) -> GEMM3 (f32 out).

typedef __attribute__((ext_vector_type(8))) __bf16 bf16x8;
typedef __attribute__((ext_vector_type(4))) __bf16 bf16x4;
typedef __attribute__((ext_vector_type(4))) float  f32x4;

#define LOG2E 1.4426950408889634f
#define SM_SC (0.125f * LOG2E)   // softmax scale folded with log2(e)

static __device__ __forceinline__ void gl2lds16(const void* g, void* l) {
    __builtin_amdgcn_global_load_lds(
        (__attribute__((address_space(1))) void*)(void*)g,
        (__attribute__((address_space(3))) void*)l, 16, 0, 0);
}

// ---------------- prep kernels ----------------
__global__ void prep_x_kern(const float* __restrict__ x, __bf16* __restrict__ xb) {
    int i = (blockIdx.x * 256 + threadIdx.x) * 4;
    f32x4 v = *(const f32x4*)(x + i);
    bf16x4 o = { (__bf16)v[0], (__bf16)v[1], (__bf16)v[2], (__bf16)v[3] };
    *(bf16x4*)(xb + i) = o;
}

// wt[n][k] = W_p[h][k][d],  n = p*1024 + h*64 + d (p in {q,k,v}); bias[n] = b_p[h*64+d]
__global__ void prep_wqkv_kern(const float* __restrict__ Wq, const float* __restrict__ Wk,
                               const float* __restrict__ Wv, const float* __restrict__ bq,
                               const float* __restrict__ bk, const float* __restrict__ bv,
                               __bf16* __restrict__ wt, float* __restrict__ bias) {
    int idx = blockIdx.x * 256 + threadIdx.x;     // 0..3145727
    int n = idx >> 10, kk = idx & 1023;
    int p = n >> 10, rm = n & 1023;
    int h = rm >> 6, d = rm & 63;
    const float* W = (p == 0) ? Wq : (p == 1) ? Wk : Wv;
    wt[idx] = (__bf16)W[(h << 16) + (kk << 6) + d];
    if (idx < 3072) {
        int p2 = idx >> 10, rm2 = idx & 1023;
        const float* bb = (p2 == 0) ? bq : (p2 == 1) ? bk : bv;
        bias[idx] = bb[rm2];
    }
}

// wt[n][k] = W_o[k][n]
__global__ void prep_wo_kern(const float* __restrict__ Wo, __bf16* __restrict__ wt) {
    int idx = blockIdx.x * 256 + threadIdx.x;    // 0..1048575
    int n = idx >> 10, kk = idx & 1023;
    wt[idx] = (__bf16)Wo[(kk << 10) + n];
}

// ---------------- GEMM: C[M][N] = A[M][1024] * Bt[N][1024]^T (+bias) ----------------
// 128x128 tile, BK=64, 4 waves each computing 64x64 via 4x4 of 16x16x32 MFMA.
// EPI=0: scatter bf16 into q/k ([bh][s][d]) and vT ([bh][d][s]) per n = p*1024+h*64+d
// EPI=1: f32 out + bias
template <int EPI>
__global__ void __launch_bounds__(256, 2)
gemm_bt(const __bf16* __restrict__ A, const __bf16* __restrict__ Bt,
        const float* __restrict__ bias,
        __bf16* __restrict__ outq, __bf16* __restrict__ outk, __bf16* __restrict__ outv,
        float* __restrict__ outf)
{
    __shared__ __align__(16) __bf16 As[128 * 64];
    __shared__ __align__(16) __bf16 Bs[128 * 64];
    const int tid = threadIdx.x;
    const int wid = tid >> 6, lane = tid & 63;
    const int r = lane & 15, g = lane >> 4;
    const int m0 = blockIdx.y << 7, n0 = blockIdx.x << 7;
    const int wr = wid >> 1, wc = wid & 1;
    f32x4 acc[4][4] = {};
    for (int k0 = 0; k0 < 1024; k0 += 64) {
        #pragma unroll
        for (int c = 0; c < 4; ++c) {
            int cq = (c * 4 + wid) * 64 + lane;   // 16B chunk index in [0,1024)
            int row = cq >> 3, ci = cq & 7;
            gl2lds16(A  + (((size_t)(m0 + row)) << 10) + k0 + ci * 8, As + (c * 4 + wid) * 512);
            gl2lds16(Bt + (((size_t)(n0 + row)) << 10) + k0 + ci * 8, Bs + (c * 4 + wid) * 512);
        }
        __syncthreads();
        bf16x8 af[2][4], bfr[2][4];
        #pragma unroll
        for (int kh = 0; kh < 2; ++kh)
            #pragma unroll
            for (int i = 0; i < 4; ++i) {
                af[kh][i]  = *(const bf16x8*)&As[(wr * 64 + i * 16 + r) * 64 + kh * 32 + g * 8];
                bfr[kh][i] = *(const bf16x8*)&Bs[(wc * 64 + i * 16 + r) * 64 + kh * 32 + g * 8];
            }
        #pragma unroll
        for (int kh = 0; kh < 2; ++kh)
            #pragma unroll
            for (int mi = 0; mi < 4; ++mi)
                #pragma unroll
                for (int ni = 0; ni < 4; ++ni)
                    acc[mi][ni] = __builtin_amdgcn_mfma_f32_16x16x32_bf16(
                        af[kh][mi], bfr[kh][ni], acc[mi][ni], 0, 0, 0);
        __syncthreads();
    }
    if (EPI == 0) {
        #pragma unroll
        for (int ni = 0; ni < 4; ++ni) {
            int n = n0 + wc * 64 + ni * 16 + r;
            float bv = bias[n];
            int p = n >> 10, rem = n & 1023, h = rem >> 6, d = rem & 63;
            #pragma unroll
            for (int mi = 0; mi < 4; ++mi) {
                int mb = m0 + wr * 64 + mi * 16 + g * 4;
                int b = mb >> 11, s = mb & 2047;
                f32x4 v = acc[mi][ni];
                if (p < 2) {
                    __bf16* dst = (p == 0) ? outq : outk;
                    size_t base = (((size_t)(b * 16 + h)) * 2048 + s) * 64 + d;
                    #pragma unroll
                    for (int j = 0; j < 4; ++j)
                        dst[base + (size_t)j * 64] = (__bf16)(v[j] + bv);
                } else {
                    bf16x4 pk = { (__bf16)(v[0] + bv), (__bf16)(v[1] + bv),
                                  (__bf16)(v[2] + bv), (__bf16)(v[3] + bv) };
                    *(bf16x4*)&outv[(((size_t)(b * 16 + h)) * 64 + d) * 2048 + s] = pk;
                }
            }
        }
    } else {
        #pragma unroll
        for (int ni = 0; ni < 4; ++ni) {
            int n = n0 + wc * 64 + ni * 16 + r;
            float bv = bias[n];
            #pragma unroll
            for (int mi = 0; mi < 4; ++mi) {
                int mb = m0 + wr * 64 + mi * 16 + g * 4;
                f32x4 v = acc[mi][ni];
                #pragma unroll
                for (int j = 0; j < 4; ++j)
                    outf[((size_t)(mb + j) << 10) + n] = v[j] + bv;
            }
        }
    }
}

// ---------------- flash attention ----------------
// grid (16, 32): x = 128-row Q-block (reversed for LPT), y = b*16+h.
// 8 waves x 16 q-rows. K tile [64 n][64 d], V^T tile [64 d][64 n] in padded LDS.
// Async-stage split: next tile's K/V global loads issued before compute,
// LDS writes after the barrier.
__global__ void __launch_bounds__(512, 4)
attn_kern(const __bf16* __restrict__ q, const __bf16* __restrict__ k,
          const __bf16* __restrict__ vT, __bf16* __restrict__ o)
{
    __shared__ __align__(16) __bf16 Ks[64][72];
    __shared__ __align__(16) __bf16 Vs[64][72];
    __shared__ __align__(16) __bf16 Ps[8][16][72];
    const int tid = threadIdx.x, w = tid >> 6, lane = tid & 63;
    const int r = lane & 15, g = lane >> 4;
    const int bh = blockIdx.y;
    const int b = bh >> 4, h = bh & 15;
    const int xq = (int)gridDim.x - 1 - (int)blockIdx.x;   // LPT: heavy blocks first
    const int qb0 = xq << 7;
    const __bf16* qh  = q  + ((size_t)bh << 17);  // [2048][64]
    const __bf16* khp = k  + ((size_t)bh << 17);
    const __bf16* vhp = vT + ((size_t)bh << 17);  // [64][2048]

    const int wrow0 = qb0 + w * 16;               // wave's first q-row

    bf16x8 qf[2];
    #pragma unroll
    for (int kc = 0; kc < 2; ++kc)
        qf[kc] = *(const bf16x8*)&qh[(size_t)(wrow0 + r) * 64 + kc * 32 + g * 8];

    f32x4 oacc[4] = {};
    float mrun[4], lrun[4];
    #pragma unroll
    for (int j = 0; j < 4; ++j) { mrun[j] = -3.0e38f; lrun[j] = 0.f; }

    const int srow = tid >> 3, sci = tid & 7;     // staging coords: 512 thr = 64x64 tile
    // prologue: stage tile 0
    *(bf16x8*)&Ks[srow][sci * 8] = *(const bf16x8*)&khp[(size_t)srow * 64 + sci * 8];
    *(bf16x8*)&Vs[srow][sci * 8] = *(const bf16x8*)&vhp[(size_t)srow * 2048 + sci * 8];
    __syncthreads();

    const int ntiles = (qb0 >> 6) + 2;
    for (int t = 0; t < ntiles; ++t) {
        const int n0 = t << 6;
        const bool pre = (t + 1 < ntiles);
        bf16x8 nk, nv;
        if (pre) {   // issue next tile's loads now; HBM latency hides under compute
            int n1 = n0 + 64;
            nk = *(const bf16x8*)&khp[(size_t)(n1 + srow) * 64 + sci * 8];
            nv = *(const bf16x8*)&vhp[(size_t)srow * 2048 + n1 + sci * 8];
        }
        const bool active = (n0 <= wrow0 + 15);
        if (active) {
            f32x4 sacc[4] = {};
            #pragma unroll
            for (int kc = 0; kc < 2; ++kc) {
                bf16x8 kf[4];
                #pragma unroll
                for (int ni = 0; ni < 4; ++ni) kf[ni] = *(const bf16x8*)&Ks[ni * 16 + r][kc * 32 + g * 8];
                #pragma unroll
                for (int ni = 0; ni < 4; ++ni)
                    sacc[ni] = __builtin_amdgcn_mfma_f32_16x16x32_bf16(
                        qf[kc], kf[ni], sacc[ni], 0, 0, 0);
            }
            if (n0 + 63 > wrow0) {   // wave-uniform: tile touches the diagonal
                int rowa = wrow0 + g * 4;
                #pragma unroll
                for (int ni = 0; ni < 4; ++ni) {
                    int cola = n0 + ni * 16 + r;
                    #pragma unroll
                    for (int j = 0; j < 4; ++j)
                        if (cola > rowa + j) sacc[ni][j] = -3.0e38f;
                }
            }
            float fac[4];
            #pragma unroll
            for (int j = 0; j < 4; ++j) {
                float rm = fmaxf(fmaxf(sacc[0][j], sacc[1][j]),
                                 fmaxf(sacc[2][j], sacc[3][j]));
                rm = fmaxf(rm, __shfl_xor(rm, 1));
                rm = fmaxf(rm, __shfl_xor(rm, 2));
                rm = fmaxf(rm, __shfl_xor(rm, 4));
                rm = fmaxf(rm, __shfl_xor(rm, 8));
                float mnew = fmaxf(mrun[j], rm);
                float f = exp2f((mrun[j] - mnew) * SM_SC);
                float ps = 0.f;
                #pragma unroll
                for (int ni = 0; ni < 4; ++ni) {
                    float pv = exp2f((sacc[ni][j] - mnew) * SM_SC);
                    sacc[ni][j] = pv;
                    ps += pv;
                }
                ps += __shfl_xor(ps, 1); ps += __shfl_xor(ps, 2);
                ps += __shfl_xor(ps, 4); ps += __shfl_xor(ps, 8);
                lrun[j] = lrun[j] * f + ps;
                mrun[j] = mnew;
                fac[j] = f;
            }
            #pragma unroll
            for (int ni = 0; ni < 4; ++ni)
                #pragma unroll
                for (int j = 0; j < 4; ++j)
                    Ps[w][g * 4 + j][ni * 16 + r] = (__bf16)sacc[ni][j];
            #pragma unroll
            for (int di = 0; di < 4; ++di)
                #pragma unroll
                for (int j = 0; j < 4; ++j)
                    oacc[di][j] *= fac[j];
            // Ps is wave-private: no barrier needed before PV (lgkmcnt only)
            #pragma unroll
            for (int kc = 0; kc < 2; ++kc) {
                bf16x8 pf, vf[4];
                pf = *(const bf16x8*)&Ps[w][r][kc * 32 + g * 8];
                #pragma unroll
                for (int di = 0; di < 4; ++di) vf[di] = *(const bf16x8*)&Vs[di * 16 + r][kc * 32 + g * 8];
                #pragma unroll
                for (int di = 0; di < 4; ++di)
                    oacc[di] = __builtin_amdgcn_mfma_f32_16x16x32_bf16(
                        pf, vf[di], oacc[di], 0, 0, 0);
            }
        }
        __syncthreads();
        if (pre) {
            *(bf16x8*)&Ks[srow][sci * 8] = nk;
            *(bf16x8*)&Vs[srow][sci * 8] = nv;
        }
        __syncthreads();
    }
    #pragma unroll
    for (int j = 0; j < 4; ++j) {
        float inv = 1.0f / lrun[j];
        int sr = wrow0 + g * 4 + j;
        #pragma unroll
        for (int di = 0; di < 4; ++di)
            o[((size_t)(b * 2048 + sr) << 10) + h * 64 + di * 16 + r] =
                (__bf16)(oacc[di][j] * inv);
    }
}

// ---------------- launch ----------------
extern "C" void kernel_launch(void* const* d_in, const int* in_sizes, int n_in,
                              void* d_out, int out_size, void* d_ws, size_t ws_size,
                              hipStream_t stream) {
    const float* x  = (const float*)d_in[0];
    const float* Wq = (const float*)d_in[1];
    const float* bq = (const float*)d_in[2];
    const float* Wk = (const float*)d_in[3];
    const float* bk = (const float*)d_in[4];
    const float* Wv = (const float*)d_in[5];
    const float* bv = (const float*)d_in[6];
    const float* Wo = (const float*)d_in[7];
    const float* bo = (const float*)d_in[8];
    float* out = (float*)d_out;
    char* ws = (char*)d_ws;
    // workspace layout (bytes), total ~48 MB
    __bf16* xb    = (__bf16*)(ws + 0);          //  8 MB  x as bf16 [4096][1024]
    __bf16* wtqkv = (__bf16*)(ws + 8388608);    //  6 MB  fused qkv weights^T [3072][1024]
    __bf16* wot   = (__bf16*)(ws + 14680064);   //  2 MB  W_o^T [1024][1024]
    float*  biasq = (float*) (ws + 16777216);   // 12 KB  fused qkv bias
    __bf16* qb    = (__bf16*)(ws + 16793600);   //  8 MB  q [32][2048][64]
    __bf16* kb    = (__bf16*)(ws + 25182208);   //  8 MB  k [32][2048][64]
    __bf16* vtb   = (__bf16*)(ws + 33570816);   //  8 MB  v^T [32][64][2048]
    __bf16* ob    = (__bf16*)(ws + 41959424);   //  8 MB  attn out [4096][1024]

    prep_x_kern<<<4096, 256, 0, stream>>>(x, xb);
    prep_wqkv_kern<<<12288, 256, 0, stream>>>(Wq, Wk, Wv, bq, bk, bv, wtqkv, biasq);
    prep_wo_kern<<<4096, 256, 0, stream>>>(Wo, wot);
    gemm_bt<0><<<dim3(24, 32), 256, 0, stream>>>(xb, wtqkv, biasq, qb, kb, vtb, nullptr);
    attn_kern<<<dim3(16, 32), 512, 0, stream>>>(qb, kb, vtb, ob);
    gemm_bt<1><<<dim3(8, 32), 256, 0, stream>>>(ob, wot, bo, nullptr, nullptr, nullptr, out);
}